// Round 7
// baseline (509.964 us; speedup 1.0000x reference)
//
#include <hip/hip_runtime.h>
#include <hip/hip_bf16.h>
#include <stdint.h>
#include <stddef.h>

typedef __bf16 bf16x8 __attribute__((ext_vector_type(8)));
typedef float f32x4 __attribute__((ext_vector_type(4)));
typedef int i32x4 __attribute__((ext_vector_type(4)));
typedef __hip_bfloat16 bf16_t;

#define BM 128
#define BN 128
#define BK 64      // bf16 elements per K-tile (128 B rows)
#define BKQ 128    // i8 elements per K-tile (128 B rows -- same geometry)
#define THREADS 256

// async global->LDS, 16B per lane. LDS dest must be wave-uniform-base + lane*16.
__device__ __forceinline__ void stage16(const void* g, void* l) {
  __builtin_amdgcn_global_load_lds(
      (const __attribute__((address_space(1))) uint32_t*)g,
      (__attribute__((address_space(3))) uint32_t*)l, 16, 0, 0);
}

__device__ __forceinline__ unsigned pk2(float x, float y) {
  bf16_t a = __float2bfloat16(x);
  bf16_t b = __float2bfloat16(y);
  unsigned short ua = *(unsigned short*)&a;
  unsigned short ub = *(unsigned short*)&b;
  return (unsigned)ua | ((unsigned)ub << 16);
}

// wave-reduce max (m >= 0), one atomicMax per wave (positive floats order as uints)
__device__ __forceinline__ void atomic_absmax(float m, unsigned* slot) {
#pragma unroll
  for (int off = 32; off > 0; off >>= 1)
    m = fmaxf(m, __shfl_xor(m, off, 64));
  if ((threadIdx.x & 63) == 0) atomicMax(slot, __float_as_uint(m));
}

// ---------------- bf16 GEMM (R3-verified core; support GEMMs) ----------------
// C = A @ Bt^T. A:[M,K] row-major bf16 (row stride K, extent Kc). Bt:[N,K].
// OUT_MODE 0: bf16 row-major [M,N]; 1: bf16 transposed [N,M]; 2: f32 row-major.
// blockIdx.z = kz*4 + b. TRACK: atomicMax of |out| into slot (OUT_MODE 1 path).
// DO NOT MODIFY staging/LDS scheme (R4: 32-row fragments -> 1.7e7 conflicts).
template <int OUT_MODE, bool RELU, bool TRACK>
__global__ void gemm_bt(const bf16_t* __restrict__ A, const bf16_t* __restrict__ Bt,
                        void* __restrict__ Cv, int M, int N, int K, int Kc,
                        long sA, long sB, long sC, unsigned* __restrict__ slot) {
  __shared__ __align__(16) char lds[(BM + BN) * BK * 2];  // 32 KB
  char* ldsA = lds;
  char* ldsB = lds + BM * BK * 2;

  const int t = threadIdx.x;
  const int lane = t & 63;
  const int w = t >> 6;
  const int wm = w >> 1, wn = w & 1;
  const int quad = lane >> 4, l15 = lane & 15;
  const int m0 = blockIdx.x * BM;
  const int n0 = blockIdx.y * BN;
  const int z = blockIdx.z;
  const int b = z & 3;
  const int kz = z >> 2;

  const bf16_t* Ab = A + (size_t)b * sA + (size_t)kz * Kc;
  const bf16_t* Bb = Bt + (size_t)b * sB + (size_t)kz * Kc;

  size_t aSrc[4], bSrc[4];
#pragma unroll
  for (int i = 0; i < 4; ++i) {
    int c = i * 256 + t;
    int r = c >> 3;
    int kcs = (c & 7) ^ (r & 7);
    aSrc[i] = (size_t)(m0 + r) * K + (size_t)kcs * 8;
    bSrc[i] = (size_t)(n0 + r) * K + (size_t)kcs * 8;
  }

  f32x4 acc[4][4];
#pragma unroll
  for (int mi = 0; mi < 4; ++mi)
#pragma unroll
    for (int ni = 0; ni < 4; ++ni)
      acc[mi][ni] = f32x4{0.f, 0.f, 0.f, 0.f};

  const int aRowB = (wm * 64 + l15) * (BK * 2);
  const int bRowB = (wn * 64 + l15) * (BK * 2);
  const int xc0 = (quad ^ (lane & 7)) * 16;

  for (int k0 = 0; k0 < Kc; k0 += BK) {
#pragma unroll
    for (int i = 0; i < 4; ++i) {
      stage16(Ab + aSrc[i] + k0, ldsA + (i * 256 + t) * 16);
      stage16(Bb + bSrc[i] + k0, ldsB + (i * 256 + t) * 16);
    }
    __syncthreads();

#pragma unroll
    for (int ks = 0; ks < 2; ++ks) {
      const int xo = xc0 ^ (ks * 64);
      bf16x8 af[4], bfr[4];
#pragma unroll
      for (int mi = 0; mi < 4; ++mi)
        af[mi] = *(const bf16x8*)(ldsA + aRowB + mi * 2048 + xo);
#pragma unroll
      for (int ni = 0; ni < 4; ++ni)
        bfr[ni] = *(const bf16x8*)(ldsB + bRowB + ni * 2048 + xo);
#pragma unroll
      for (int mi = 0; mi < 4; ++mi)
#pragma unroll
        for (int ni = 0; ni < 4; ++ni)
          acc[mi][ni] = __builtin_amdgcn_mfma_f32_16x16x32_bf16(
              af[mi], bfr[ni], acc[mi][ni], 0, 0, 0);
    }
    __syncthreads();
  }

  const int mBase = m0 + wm * 64 + quad * 4;
  const int nBase = n0 + wn * 64 + l15;
  float tmax = 0.f;

  if (OUT_MODE == 1) {
    bf16_t* Ct = (bf16_t*)Cv + (size_t)z * sC;
#pragma unroll
    for (int ni = 0; ni < 4; ++ni) {
      size_t colOff = (size_t)(nBase + ni * 16) * (size_t)M;
#pragma unroll
      for (int mi = 0; mi < 4; ++mi) {
        int rr = mBase + mi * 16;
        float v0 = acc[mi][ni][0], v1 = acc[mi][ni][1];
        float v2 = acc[mi][ni][2], v3 = acc[mi][ni][3];
        if (RELU) {
          v0 = fmaxf(v0, 0.f); v1 = fmaxf(v1, 0.f);
          v2 = fmaxf(v2, 0.f); v3 = fmaxf(v3, 0.f);
        }
        if (TRACK) {
          tmax = fmaxf(tmax, fmaxf(fmaxf(fabsf(v0), fabsf(v1)),
                                   fmaxf(fabsf(v2), fabsf(v3))));
        }
        uint2 pkv;
        pkv.x = pk2(v0, v1);
        pkv.y = pk2(v2, v3);
        *(uint2*)(Ct + colOff + rr) = pkv;
      }
    }
    if (TRACK) atomic_absmax(tmax, slot);
  } else if (OUT_MODE == 0) {
    bf16_t* C = (bf16_t*)Cv + (size_t)z * sC;
#pragma unroll
    for (int mi = 0; mi < 4; ++mi) {
#pragma unroll
      for (int j = 0; j < 4; ++j) {
        size_t rowOff = (size_t)(mBase + mi * 16 + j) * (size_t)N;
#pragma unroll
        for (int ni = 0; ni < 4; ++ni) {
          float v = acc[mi][ni][j];
          if (RELU) v = fmaxf(v, 0.f);
          C[rowOff + nBase + ni * 16] = __float2bfloat16(v);
        }
      }
    }
  } else {
    float* C = (float*)Cv + (size_t)z * sC;
#pragma unroll
    for (int mi = 0; mi < 4; ++mi) {
#pragma unroll
      for (int j = 0; j < 4; ++j) {
        size_t rowOff = (size_t)(mBase + mi * 16 + j) * (size_t)N;
#pragma unroll
        for (int ni = 0; ni < 4; ++ni) {
          float v = acc[mi][ni][j];
          if (RELU) v = fmaxf(v, 0.f);
          C[rowOff + nBase + ni * 16] = v;
        }
      }
    }
  }
}

// ---------------- int8 GEMM (adjacency GEMMs) ----------------
// Same tile/staging/swizzle geometry as gemm_bt: BKQ=128 i8 = 128 B rows =
// 8 x 16B chunks. K-step = 64 i8 = 4 chunks, ks in {0,1}; address code is
// byte-identical to the verified bf16 core. A: AW_q (scale 127, values [0,1)).
// B: dynamic per-tensor scale mx in *slot. Epilogue: v = acc * mx / 127^2.
// Output: bf16 row-major partial chunk at z*sC.
__global__ void gemm_i8(const int8_t* __restrict__ A, const int8_t* __restrict__ Bt,
                        bf16_t* __restrict__ C, int M, int N, int K, int Kc,
                        long sA, long sB, long sC,
                        const unsigned* __restrict__ slot) {
  __shared__ __align__(16) char lds[(BM + BN) * BKQ];  // 32 KB
  char* ldsA = lds;
  char* ldsB = lds + BM * BKQ;

  const int t = threadIdx.x;
  const int lane = t & 63;
  const int w = t >> 6;
  const int wm = w >> 1, wn = w & 1;
  const int quad = lane >> 4, l15 = lane & 15;
  const int m0 = blockIdx.x * BM;
  const int n0 = blockIdx.y * BN;
  const int z = blockIdx.z;
  const int b = z & 3;
  const int kz = z >> 2;

  const int8_t* Ab = A + (size_t)b * sA + (size_t)kz * Kc;
  const int8_t* Bb = Bt + (size_t)b * sB + (size_t)kz * Kc;

  size_t aSrc[4], bSrc[4];
#pragma unroll
  for (int i = 0; i < 4; ++i) {
    int c = i * 256 + t;
    int r = c >> 3;
    int kcs = (c & 7) ^ (r & 7);
    aSrc[i] = (size_t)(m0 + r) * K + (size_t)kcs * 16;  // 16 i8 per chunk
    bSrc[i] = (size_t)(n0 + r) * K + (size_t)kcs * 16;
  }

  i32x4 acc[4][4];
#pragma unroll
  for (int mi = 0; mi < 4; ++mi)
#pragma unroll
    for (int ni = 0; ni < 4; ++ni)
      acc[mi][ni] = i32x4{0, 0, 0, 0};

  const int aRowB = (wm * 64 + l15) * BKQ;
  const int bRowB = (wn * 64 + l15) * BKQ;
  const int xc0 = (quad ^ (lane & 7)) * 16;

  for (int k0 = 0; k0 < Kc; k0 += BKQ) {
#pragma unroll
    for (int i = 0; i < 4; ++i) {
      stage16(Ab + aSrc[i] + k0, ldsA + (i * 256 + t) * 16);
      stage16(Bb + bSrc[i] + k0, ldsB + (i * 256 + t) * 16);
    }
    __syncthreads();

#pragma unroll
    for (int ks = 0; ks < 2; ++ks) {        // two K=64 MFMA steps per BKQ=128
      const int xo = xc0 ^ (ks * 64);
      i32x4 af[4], bfr[4];
#pragma unroll
      for (int mi = 0; mi < 4; ++mi)
        af[mi] = *(const i32x4*)(ldsA + aRowB + mi * 2048 + xo);
#pragma unroll
      for (int ni = 0; ni < 4; ++ni)
        bfr[ni] = *(const i32x4*)(ldsB + bRowB + ni * 2048 + xo);
#pragma unroll
      for (int mi = 0; mi < 4; ++mi)
#pragma unroll
        for (int ni = 0; ni < 4; ++ni)
          acc[mi][ni] = __builtin_amdgcn_mfma_i32_16x16x64_i8(
              af[mi], bfr[ni], acc[mi][ni], 0, 0, 0);
    }
    __syncthreads();
  }

  const float mx = fmaxf(__uint_as_float(*slot), 1e-20f);
  const float sc = mx * (1.0f / 16129.0f);  // / (127*127)

  const int mBase = m0 + wm * 64 + quad * 4;
  const int nBase = n0 + wn * 64 + l15;
  bf16_t* Cb = C + (size_t)z * sC;
#pragma unroll
  for (int mi = 0; mi < 4; ++mi) {
#pragma unroll
    for (int j = 0; j < 4; ++j) {
      size_t rowOff = (size_t)(mBase + mi * 16 + j) * (size_t)N;
#pragma unroll
      for (int ni = 0; ni < 4; ++ni)
        Cb[rowOff + nBase + ni * 16] = __float2bfloat16((float)acc[mi][ni][j] * sc);
    }
  }
}

// Sum SK bf16 partial chunks (stride tot) in fp32; write bf16 or f32.
// TRACK: atomicMax |result| into slot (used where the reduce produces a
// to-be-quantized tensor, so the scale is exact).
template <int SK, bool F32OUT, bool TRACK>
__global__ void reduce_k(const bf16_t* __restrict__ pp, void* __restrict__ out,
                         size_t tot, unsigned* __restrict__ slot) {
  size_t i = ((size_t)blockIdx.x * blockDim.x + threadIdx.x) * 8;
  if (i >= tot) return;
  float s[8] = {0.f, 0.f, 0.f, 0.f, 0.f, 0.f, 0.f, 0.f};
#pragma unroll
  for (int kz = 0; kz < SK; ++kz) {
    bf16x8 v = *(const bf16x8*)(pp + kz * tot + i);
#pragma unroll
    for (int j = 0; j < 8; ++j) s[j] += (float)v[j];
  }
  if (TRACK) {
    float m = 0.f;
#pragma unroll
    for (int j = 0; j < 8; ++j) m = fmaxf(m, fabsf(s[j]));
    atomic_absmax(m, slot);
  }
  if (F32OUT) {
    float* o = (float*)out + i;
#pragma unroll
    for (int j = 0; j < 8; ++j) o[j] = s[j];
  } else {
    uint4 r;
    r.x = pk2(s[0], s[1]);
    r.y = pk2(s[2], s[3]);
    r.z = pk2(s[4], s[5]);
    r.w = pk2(s[6], s[7]);
    *(uint4*)((bf16_t*)out + i) = r;
  }
}

// AW_q = round(adj*S*127), clamped [-127,127]; inputs in [0,1) for this data.
__global__ void mul_cast_q(const float* __restrict__ a, const float* __restrict__ s,
                           int8_t* __restrict__ o, int n4) {
  int i = blockIdx.x * blockDim.x + threadIdx.x;
  if (i < n4) {
    float4 av = ((const float4*)a)[i];
    float4 sv = ((const float4*)s)[i];
    float v0 = av.x * sv.x * 127.f, v1 = av.y * sv.y * 127.f;
    float v2 = av.z * sv.z * 127.f, v3 = av.w * sv.w * 127.f;
    int q0 = (int)rintf(fminf(fmaxf(v0, -127.f), 127.f));
    int q1 = (int)rintf(fminf(fmaxf(v1, -127.f), 127.f));
    int q2 = (int)rintf(fminf(fmaxf(v2, -127.f), 127.f));
    int q3 = (int)rintf(fminf(fmaxf(v3, -127.f), 127.f));
    unsigned p = (unsigned)(q0 & 255) | ((unsigned)(q1 & 255) << 8) |
                 ((unsigned)(q2 & 255) << 16) | ((unsigned)(q3 & 255) << 24);
    ((unsigned*)o)[i] = p;
  }
}

// grid-stride absmax over f32 array (as float4), atomicMax into slot
__global__ void absmax_f32(const float* __restrict__ p, size_t n4,
                           unsigned* __restrict__ slot) {
  size_t i = (size_t)blockIdx.x * blockDim.x + threadIdx.x;
  size_t stride = (size_t)gridDim.x * blockDim.x;
  float m = 0.f;
  for (; i < n4; i += stride) {
    float4 v = ((const float4*)p)[i];
    m = fmaxf(m, fmaxf(fmaxf(fabsf(v.x), fabsf(v.y)),
                       fmaxf(fabsf(v.z), fabsf(v.w))));
  }
  atomic_absmax(m, slot);
}

// x [B][4096][256] f32 -> xt [B][256][4096] i8 (scale 127/mx from slot)
__global__ void transpose_quant_x(const float* __restrict__ x, int8_t* __restrict__ xt,
                                  const unsigned* __restrict__ slot) {
  __shared__ float tile[32][33];
  const int N = 4096, F = 256;
  float qs = 127.0f / fmaxf(__uint_as_float(*slot), 1e-20f);
  int n0 = blockIdx.x * 32, f0 = blockIdx.y * 32, b = blockIdx.z;
  const float* xb = x + (size_t)b * N * F;
  int8_t* xtb = xt + (size_t)b * N * F;
  int tx = threadIdx.x & 31, ty = threadIdx.x >> 5;  // 32 x 8
#pragma unroll
  for (int i = 0; i < 32; i += 8)
    tile[ty + i][tx] = xb[(size_t)(n0 + ty + i) * F + f0 + tx];
  __syncthreads();
#pragma unroll
  for (int i = 0; i < 32; i += 8) {
    float v = tile[tx][ty + i] * qs;
    xtb[(size_t)(f0 + ty + i) * N + n0 + tx] =
        (int8_t)(int)rintf(fminf(fmaxf(v, -127.f), 127.f));
  }
}

// bf16 -> i8 with scale 127/mx from slot; 8 elems/thread
__global__ void quant8(const bf16_t* __restrict__ in, int8_t* __restrict__ out,
                       const unsigned* __restrict__ slot, size_t n8) {
  size_t i = (size_t)blockIdx.x * blockDim.x + threadIdx.x;
  if (i >= n8) return;
  float qs = 127.0f / fmaxf(__uint_as_float(*slot), 1e-20f);
  bf16x8 v = *(const bf16x8*)(in + i * 8);
  unsigned lo = 0, hi = 0;
#pragma unroll
  for (int j = 0; j < 4; ++j) {
    int q = (int)rintf(fminf(fmaxf((float)v[j] * qs, -127.f), 127.f));
    lo |= (unsigned)(q & 255) << (8 * j);
  }
#pragma unroll
  for (int j = 0; j < 4; ++j) {
    int q = (int)rintf(fminf(fmaxf((float)v[4 + j] * qs, -127.f), 127.f));
    hi |= (unsigned)(q & 255) << (8 * j);
  }
  uint2 r{lo, hi};
  ((uint2*)out)[i] = r;
}

// All three weight transposes in one launch. wt[h*K + k] = bf16(w[k*H + h]).
__global__ void transpose_cast3_kernel(const float* __restrict__ W1, const float* __restrict__ W2,
                                       const float* __restrict__ W3, bf16_t* __restrict__ W1T,
                                       bf16_t* __restrict__ W2T, bf16_t* __restrict__ W3T) {
  const int n1 = 256 * 512;
  const int n2 = 512 * 1024;
  const int n3 = 1024 * 256;
  int idx = blockIdx.x * blockDim.x + threadIdx.x;
  if (idx < n1) {
    int K = 256, H = 512;
    int h = idx / K, k = idx - h * K;
    W1T[idx] = __float2bfloat16(W1[(size_t)k * H + h]);
  } else if (idx < n1 + n2) {
    int i = idx - n1;
    int K = 512, H = 1024;
    int h = i / K, k = i - h * K;
    W2T[i] = __float2bfloat16(W2[(size_t)k * H + h]);
  } else if (idx < n1 + n2 + n3) {
    int i = idx - n1 - n2;
    int K = 1024, H = 256;
    int h = i / K, k = i - h * K;
    W3T[i] = __float2bfloat16(W3[(size_t)k * H + h]);
  }
}

__global__ void init_scales(unsigned* s) {
  if (threadIdx.x < 3) s[threadIdx.x] = 0u;
}

extern "C" void kernel_launch(void* const* d_in, const int* in_sizes, int n_in,
                              void* d_out, int out_size, void* d_ws, size_t ws_size,
                              hipStream_t stream) {
  const float* x   = (const float*)d_in[0];  // [4, 4096, 256]
  const float* adj = (const float*)d_in[1];  // [4096, 4096]
  const float* S   = (const float*)d_in[2];  // [4096, 4096]
  const float* W1  = (const float*)d_in[3];  // [256, 512]
  const float* W2  = (const float*)d_in[4];  // [512, 1024]
  const float* W3  = (const float*)d_in[5];  // [1024, 256]

  const int N = 4096, F = 256, H1 = 512, H2 = 1024, NC = 256, B = 4;

  // Chain (adjacency GEMMs in i8, support GEMMs bf16):
  //   g1 = AWq @ xq (SK=4)           ; h1^T = relu((g1 @ W1))^T   [track max]
  //   g2 = AWq @ h1q (SK=2)          ; h2 = relu(g2 @ W2)
  //   st3^T = (h2 @ W3)^T (SK=2)     [track max in reduce]
  //   out = AWq @ st3q (SK=4, f32 via reduce)
  // Workspace ~98.5 MiB.
  char* ws = (char*)d_ws;
  int8_t* AWQ  = (int8_t*)ws; ws += (size_t)N * N;           // 16.8 MB
  bf16_t* SCR  = (bf16_t*)ws; ws += (size_t)B * N * H2 * 2;  // 33.5 MB partials/H2B
  int8_t* XQT  = (int8_t*)ws; ws += (size_t)B * F * N;       //  4.2 MB
  bf16_t* BufY = (bf16_t*)ws; ws += (size_t)B * N * H1 * 2;  // 16.8 MB G1/G2/ST3T
  bf16_t* BufZ = (bf16_t*)ws; ws += (size_t)B * N * H1 * 2;  // 16.8 MB H1T/st3 partials
  int8_t* QS   = (int8_t*)ws; ws += (size_t)B * H1 * N;      //  8.4 MB H1Q/ST3Q
  bf16_t* W1T  = (bf16_t*)ws; ws += (size_t)F * H1 * 2;
  bf16_t* W2T  = (bf16_t*)ws; ws += (size_t)H1 * H2 * 2;
  bf16_t* W3T  = (bf16_t*)ws; ws += (size_t)H2 * NC * 2;
  unsigned* SC = (unsigned*)ws;                              // 3 scale slots
  unsigned* SX = SC, *SH1 = SC + 1, *SST3 = SC + 2;

  bf16_t* G1 = BufY, *G2 = BufY, *ST3T = BufY;
  bf16_t* H1T = BufZ;
  bf16_t* H2B = SCR;
  int8_t* H1Q = QS, *ST3Q = QS;

  dim3 blk(THREADS);

  // prep
  init_scales<<<1, 64, 0, stream>>>(SC);
  mul_cast_q<<<(N * N / 4 + 255) / 256, 256, 0, stream>>>(adj, S, AWQ, N * N / 4);
  absmax_f32<<<1024, 256, 0, stream>>>(x, (size_t)B * N * F / 4, SX);
  transpose_quant_x<<<dim3(N / 32, F / 32, B), 256, 0, stream>>>(x, XQT, SX);
  {
    int total = 256 * 512 + 512 * 1024 + 1024 * 256;
    transpose_cast3_kernel<<<(total + 255) / 256, 256, 0, stream>>>(W1, W2, W3, W1T, W2T, W3T);
  }

  // L1: g1 = AWq @ xq, SK=4 -> partials SCR, reduce -> G1
  gemm_i8<<<dim3(N / BM, F / BN, B * 4), blk, 0, stream>>>(
      AWQ, XQT, SCR, N, F, N, N / 4, 0, (long)F * N, (long)N * F, SX);
  reduce_k<4, false, false><<<(B * N * F / 8) / 256, 256, 0, stream>>>(
      SCR, G1, (size_t)B * N * F, nullptr);
  //     h1^T = relu(g1 @ W1)^T -> H1T, track absmax -> SH1
  gemm_bt<1, true, true><<<dim3(N / BM, H1 / BN, B), blk, 0, stream>>>(
      G1, W1T, H1T, N, H1, F, F, (long)N * F, 0, (long)H1 * N, SH1);
  quant8<<<((int)((size_t)B * H1 * N / 8) + 255) / 256, 256, 0, stream>>>(
      H1T, H1Q, SH1, (size_t)B * H1 * N / 8);

  // L2: g2 = AWq @ h1q, SK=2 -> partials SCR, reduce -> G2
  gemm_i8<<<dim3(N / BM, H1 / BN, B * 2), blk, 0, stream>>>(
      AWQ, H1Q, SCR, N, H1, N, N / 2, 0, (long)H1 * N, (long)N * H1, SH1);
  reduce_k<2, false, false><<<(B * N * H1 / 8) / 256, 256, 0, stream>>>(
      SCR, G2, (size_t)B * N * H1, nullptr);
  //     h2 = relu(g2 @ W2) -> H2B (SCR)
  gemm_bt<0, true, false><<<dim3(N / BM, H2 / BN, B), blk, 0, stream>>>(
      G2, W2T, H2B, N, H2, H1, H1, (long)N * H1, 0, (long)N * H2, nullptr);

  // L3: st3^T = (h2 @ W3)^T, SK=2 -> partials BufZ, reduce(track) -> ST3T + SST3
  gemm_bt<1, false, false><<<dim3(N / BM, NC / BN, B * 2), blk, 0, stream>>>(
      H2B, W3T, BufZ, N, NC, H2, H2 / 2, (long)N * H2, 0, (long)NC * N, nullptr);
  reduce_k<2, false, true><<<(B * NC * N / 8) / 256, 256, 0, stream>>>(
      BufZ, ST3T, (size_t)B * NC * N, SST3);
  quant8<<<((int)((size_t)B * NC * N / 8) + 255) / 256, 256, 0, stream>>>(
      ST3T, ST3Q, SST3, (size_t)B * NC * N / 8);
  //     out = AWq @ st3q, SK=4 -> partials SCR, reduce f32 -> d_out
  gemm_i8<<<dim3(N / BM, NC / BN, B * 4), blk, 0, stream>>>(
      AWQ, ST3Q, SCR, N, NC, N, N / 4, 0, (long)NC * N, (long)N * NC, SST3);
  reduce_k<4, true, false><<<(B * N * NC / 8) / 256, 256, 0, stream>>>(
      SCR, d_out, (size_t)B * N * NC, nullptr);
}

// Round 8
// 375.575 us; speedup vs baseline: 1.3578x; 1.3578x over previous
//
#include <hip/hip_runtime.h>
#include <hip/hip_bf16.h>
#include <stdint.h>
#include <stddef.h>

typedef __bf16 bf16x8 __attribute__((ext_vector_type(8)));
typedef float f32x4 __attribute__((ext_vector_type(4)));
typedef int i32x4 __attribute__((ext_vector_type(4)));
typedef __hip_bfloat16 bf16_t;

#define BM 128
#define BN 128
#define BK 64      // bf16 elements per K-tile (128 B rows)
#define BKQ 128    // i8 elements per K-tile (128 B rows -- same geometry)
#define THREADS 256

// async global->LDS, 16B per lane. LDS dest must be wave-uniform-base + lane*16.
__device__ __forceinline__ void stage16(const void* g, void* l) {
  __builtin_amdgcn_global_load_lds(
      (const __attribute__((address_space(1))) uint32_t*)g,
      (__attribute__((address_space(3))) uint32_t*)l, 16, 0, 0);
}

__device__ __forceinline__ unsigned pk2(float x, float y) {
  bf16_t a = __float2bfloat16(x);
  bf16_t b = __float2bfloat16(y);
  unsigned short ua = *(unsigned short*)&a;
  unsigned short ub = *(unsigned short*)&b;
  return (unsigned)ua | ((unsigned)ub << 16);
}

// ---------------- bf16 GEMM (R3/R6-verified core; support GEMMs) -------------
// C = A @ Bt^T. A:[M,K] row-major bf16 (row stride K, extent Kc). Bt:[N,K].
// OUT_MODE 0: bf16 row-major [M,N]; 1: bf16 transposed [N,M]; 2: f32 row-major.
// blockIdx.z = kz*4 + b (B=4). Output chunk at z*sC.
// DO NOT MODIFY staging/LDS scheme (R4: 32-row fragments -> 1.7e7 conflicts).
// NO per-tensor atomics in here (R7: wave atomics to one address cost ~50us).
template <int OUT_MODE, bool RELU>
__global__ void gemm_bt(const bf16_t* __restrict__ A, const bf16_t* __restrict__ Bt,
                        void* __restrict__ Cv, int M, int N, int K, int Kc,
                        long sA, long sB, long sC) {
  __shared__ __align__(16) char lds[(BM + BN) * BK * 2];  // 32 KB
  char* ldsA = lds;
  char* ldsB = lds + BM * BK * 2;

  const int t = threadIdx.x;
  const int lane = t & 63;
  const int w = t >> 6;
  const int wm = w >> 1, wn = w & 1;
  const int quad = lane >> 4, l15 = lane & 15;
  const int m0 = blockIdx.x * BM;
  const int n0 = blockIdx.y * BN;
  const int z = blockIdx.z;
  const int b = z & 3;
  const int kz = z >> 2;

  const bf16_t* Ab = A + (size_t)b * sA + (size_t)kz * Kc;
  const bf16_t* Bb = Bt + (size_t)b * sB + (size_t)kz * Kc;

  size_t aSrc[4], bSrc[4];
#pragma unroll
  for (int i = 0; i < 4; ++i) {
    int c = i * 256 + t;
    int r = c >> 3;
    int kcs = (c & 7) ^ (r & 7);
    aSrc[i] = (size_t)(m0 + r) * K + (size_t)kcs * 8;
    bSrc[i] = (size_t)(n0 + r) * K + (size_t)kcs * 8;
  }

  f32x4 acc[4][4];
#pragma unroll
  for (int mi = 0; mi < 4; ++mi)
#pragma unroll
    for (int ni = 0; ni < 4; ++ni)
      acc[mi][ni] = f32x4{0.f, 0.f, 0.f, 0.f};

  const int aRowB = (wm * 64 + l15) * (BK * 2);
  const int bRowB = (wn * 64 + l15) * (BK * 2);
  const int xc0 = (quad ^ (lane & 7)) * 16;

  for (int k0 = 0; k0 < Kc; k0 += BK) {
#pragma unroll
    for (int i = 0; i < 4; ++i) {
      stage16(Ab + aSrc[i] + k0, ldsA + (i * 256 + t) * 16);
      stage16(Bb + bSrc[i] + k0, ldsB + (i * 256 + t) * 16);
    }
    __syncthreads();

#pragma unroll
    for (int ks = 0; ks < 2; ++ks) {
      const int xo = xc0 ^ (ks * 64);
      bf16x8 af[4], bfr[4];
#pragma unroll
      for (int mi = 0; mi < 4; ++mi)
        af[mi] = *(const bf16x8*)(ldsA + aRowB + mi * 2048 + xo);
#pragma unroll
      for (int ni = 0; ni < 4; ++ni)
        bfr[ni] = *(const bf16x8*)(ldsB + bRowB + ni * 2048 + xo);
#pragma unroll
      for (int mi = 0; mi < 4; ++mi)
#pragma unroll
        for (int ni = 0; ni < 4; ++ni)
          acc[mi][ni] = __builtin_amdgcn_mfma_f32_16x16x32_bf16(
              af[mi], bfr[ni], acc[mi][ni], 0, 0, 0);
    }
    __syncthreads();
  }

  const int mBase = m0 + wm * 64 + quad * 4;
  const int nBase = n0 + wn * 64 + l15;

  if (OUT_MODE == 1) {
    bf16_t* Ct = (bf16_t*)Cv + (size_t)z * sC;
#pragma unroll
    for (int ni = 0; ni < 4; ++ni) {
      size_t colOff = (size_t)(nBase + ni * 16) * (size_t)M;
#pragma unroll
      for (int mi = 0; mi < 4; ++mi) {
        int rr = mBase + mi * 16;
        float v0 = acc[mi][ni][0], v1 = acc[mi][ni][1];
        float v2 = acc[mi][ni][2], v3 = acc[mi][ni][3];
        if (RELU) {
          v0 = fmaxf(v0, 0.f); v1 = fmaxf(v1, 0.f);
          v2 = fmaxf(v2, 0.f); v3 = fmaxf(v3, 0.f);
        }
        uint2 pkv;
        pkv.x = pk2(v0, v1);
        pkv.y = pk2(v2, v3);
        *(uint2*)(Ct + colOff + rr) = pkv;
      }
    }
  } else if (OUT_MODE == 0) {
    bf16_t* C = (bf16_t*)Cv + (size_t)z * sC;
#pragma unroll
    for (int mi = 0; mi < 4; ++mi) {
#pragma unroll
      for (int j = 0; j < 4; ++j) {
        size_t rowOff = (size_t)(mBase + mi * 16 + j) * (size_t)N;
#pragma unroll
        for (int ni = 0; ni < 4; ++ni) {
          float v = acc[mi][ni][j];
          if (RELU) v = fmaxf(v, 0.f);
          C[rowOff + nBase + ni * 16] = __float2bfloat16(v);
        }
      }
    }
  } else {
    float* C = (float*)Cv + (size_t)z * sC;
#pragma unroll
    for (int mi = 0; mi < 4; ++mi) {
#pragma unroll
      for (int j = 0; j < 4; ++j) {
        size_t rowOff = (size_t)(mBase + mi * 16 + j) * (size_t)N;
#pragma unroll
        for (int ni = 0; ni < 4; ++ni) {
          float v = acc[mi][ni][j];
          if (RELU) v = fmaxf(v, 0.f);
          C[rowOff + nBase + ni * 16] = v;
        }
      }
    }
  }
}

// ---------------- int8 GEMM (adjacency GEMMs; R7-validated) ----------------
// BKQ=128 i8 = 128 B rows = same staging geometry as bf16 core. K-step = 64 i8
// = 4 chunks. A: AW_q (static scale 127). B: per-tensor scale mx in *slot.
// Epilogue: v = acc * mx / 127^2. Output bf16 row-major partial at z*sC.
__global__ void gemm_i8(const int8_t* __restrict__ A, const int8_t* __restrict__ Bt,
                        bf16_t* __restrict__ C, int M, int N, int K, int Kc,
                        long sA, long sB, long sC,
                        const unsigned* __restrict__ slot) {
  __shared__ __align__(16) char lds[(BM + BN) * BKQ];  // 32 KB
  char* ldsA = lds;
  char* ldsB = lds + BM * BKQ;

  const int t = threadIdx.x;
  const int lane = t & 63;
  const int w = t >> 6;
  const int wm = w >> 1, wn = w & 1;
  const int quad = lane >> 4, l15 = lane & 15;
  const int m0 = blockIdx.x * BM;
  const int n0 = blockIdx.y * BN;
  const int z = blockIdx.z;
  const int b = z & 3;
  const int kz = z >> 2;

  const int8_t* Ab = A + (size_t)b * sA + (size_t)kz * Kc;
  const int8_t* Bb = Bt + (size_t)b * sB + (size_t)kz * Kc;

  size_t aSrc[4], bSrc[4];
#pragma unroll
  for (int i = 0; i < 4; ++i) {
    int c = i * 256 + t;
    int r = c >> 3;
    int kcs = (c & 7) ^ (r & 7);
    aSrc[i] = (size_t)(m0 + r) * K + (size_t)kcs * 16;  // 16 i8 per chunk
    bSrc[i] = (size_t)(n0 + r) * K + (size_t)kcs * 16;
  }

  i32x4 acc[4][4];
#pragma unroll
  for (int mi = 0; mi < 4; ++mi)
#pragma unroll
    for (int ni = 0; ni < 4; ++ni)
      acc[mi][ni] = i32x4{0, 0, 0, 0};

  const int aRowB = (wm * 64 + l15) * BKQ;
  const int bRowB = (wn * 64 + l15) * BKQ;
  const int xc0 = (quad ^ (lane & 7)) * 16;

  for (int k0 = 0; k0 < Kc; k0 += BKQ) {
#pragma unroll
    for (int i = 0; i < 4; ++i) {
      stage16(Ab + aSrc[i] + k0, ldsA + (i * 256 + t) * 16);
      stage16(Bb + bSrc[i] + k0, ldsB + (i * 256 + t) * 16);
    }
    __syncthreads();

#pragma unroll
    for (int ks = 0; ks < 2; ++ks) {        // two K=64 MFMA steps per BKQ=128
      const int xo = xc0 ^ (ks * 64);
      i32x4 af[4], bfr[4];
#pragma unroll
      for (int mi = 0; mi < 4; ++mi)
        af[mi] = *(const i32x4*)(ldsA + aRowB + mi * 2048 + xo);
#pragma unroll
      for (int ni = 0; ni < 4; ++ni)
        bfr[ni] = *(const i32x4*)(ldsB + bRowB + ni * 2048 + xo);
#pragma unroll
      for (int mi = 0; mi < 4; ++mi)
#pragma unroll
        for (int ni = 0; ni < 4; ++ni)
          acc[mi][ni] = __builtin_amdgcn_mfma_i32_16x16x64_i8(
              af[mi], bfr[ni], acc[mi][ni], 0, 0, 0);
    }
    __syncthreads();
  }

  const float mx = fmaxf(__uint_as_float(*slot), 1e-20f);
  const float sc = mx * (1.0f / 16129.0f);  // / (127*127)

  const int mBase = m0 + wm * 64 + quad * 4;
  const int nBase = n0 + wn * 64 + l15;
  bf16_t* Cb = C + (size_t)z * sC;
#pragma unroll
  for (int mi = 0; mi < 4; ++mi) {
#pragma unroll
    for (int j = 0; j < 4; ++j) {
      size_t rowOff = (size_t)(mBase + mi * 16 + j) * (size_t)N;
#pragma unroll
      for (int ni = 0; ni < 4; ++ni)
        Cb[rowOff + nBase + ni * 16] = __float2bfloat16((float)acc[mi][ni][j] * sc);
    }
  }
}

// Sum SK bf16 partial chunks (stride tot) in fp32; write bf16 or f32.
// No atomics (R7 lesson).
template <int SK, bool F32OUT>
__global__ void reduce_k(const bf16_t* __restrict__ pp, void* __restrict__ out,
                         size_t tot) {
  size_t i = ((size_t)blockIdx.x * blockDim.x + threadIdx.x) * 8;
  if (i >= tot) return;
  float s[8] = {0.f, 0.f, 0.f, 0.f, 0.f, 0.f, 0.f, 0.f};
#pragma unroll
  for (int kz = 0; kz < SK; ++kz) {
    bf16x8 v = *(const bf16x8*)(pp + kz * tot + i);
#pragma unroll
    for (int j = 0; j < 8; ++j) s[j] += (float)v[j];
  }
  if (F32OUT) {
    float* o = (float*)out + i;
#pragma unroll
    for (int j = 0; j < 8; ++j) o[j] = s[j];
  } else {
    uint4 r;
    r.x = pk2(s[0], s[1]);
    r.y = pk2(s[2], s[3]);
    r.z = pk2(s[4], s[5]);
    r.w = pk2(s[6], s[7]);
    *(uint4*)((bf16_t*)out + i) = r;
  }
}

// ---------------- hierarchical absmax (1 atomic per BLOCK) ----------------
// R7 lesson: wave-level atomics to one address serialize (~12ns each across
// XCDs); 8192 of them = 97us. Block-level: 512 atomics = ~6us.
__device__ __forceinline__ void block_max_commit(float m, unsigned* slot) {
  __shared__ float red[4];
#pragma unroll
  for (int off = 32; off > 0; off >>= 1)
    m = fmaxf(m, __shfl_xor(m, off, 64));
  if ((threadIdx.x & 63) == 0) red[threadIdx.x >> 6] = m;
  __syncthreads();
  if (threadIdx.x == 0) {
    float mm = fmaxf(fmaxf(red[0], red[1]), fmaxf(red[2], red[3]));
    atomicMax(slot, __float_as_uint(mm));
  }
}

__global__ void absmax_f32_h(const float* __restrict__ p, size_t n4,
                             unsigned* __restrict__ slot) {
  size_t i = (size_t)blockIdx.x * blockDim.x + threadIdx.x;
  size_t stride = (size_t)gridDim.x * blockDim.x;
  float m = 0.f;
  for (; i < n4; i += stride) {
    float4 v = ((const float4*)p)[i];
    m = fmaxf(m, fmaxf(fmaxf(fabsf(v.x), fabsf(v.y)),
                       fmaxf(fabsf(v.z), fabsf(v.w))));
  }
  block_max_commit(m, slot);
}

__global__ void absmax_bf16_h(const bf16_t* __restrict__ p, size_t n8,
                              unsigned* __restrict__ slot) {
  size_t i = (size_t)blockIdx.x * blockDim.x + threadIdx.x;
  size_t stride = (size_t)gridDim.x * blockDim.x;
  float m = 0.f;
  for (; i < n8; i += stride) {
    bf16x8 v = *(const bf16x8*)(p + i * 8);
#pragma unroll
    for (int j = 0; j < 8; ++j) m = fmaxf(m, fabsf((float)v[j]));
  }
  block_max_commit(m, slot);
}

// AW_q = round(adj*S*127); data in [0,1).
__global__ void mul_cast_q(const float* __restrict__ a, const float* __restrict__ s,
                           int8_t* __restrict__ o, int n4) {
  int i = blockIdx.x * blockDim.x + threadIdx.x;
  if (i < n4) {
    float4 av = ((const float4*)a)[i];
    float4 sv = ((const float4*)s)[i];
    float v0 = av.x * sv.x * 127.f, v1 = av.y * sv.y * 127.f;
    float v2 = av.z * sv.z * 127.f, v3 = av.w * sv.w * 127.f;
    int q0 = (int)rintf(fminf(fmaxf(v0, -127.f), 127.f));
    int q1 = (int)rintf(fminf(fmaxf(v1, -127.f), 127.f));
    int q2 = (int)rintf(fminf(fmaxf(v2, -127.f), 127.f));
    int q3 = (int)rintf(fminf(fmaxf(v3, -127.f), 127.f));
    unsigned p = (unsigned)(q0 & 255) | ((unsigned)(q1 & 255) << 8) |
                 ((unsigned)(q2 & 255) << 16) | ((unsigned)(q3 & 255) << 24);
    ((unsigned*)o)[i] = p;
  }
}

// x [B][4096][256] f32 -> xt [B][256][4096] i8 (scale 127/mx from slot)
__global__ void transpose_quant_x(const float* __restrict__ x, int8_t* __restrict__ xt,
                                  const unsigned* __restrict__ slot) {
  __shared__ float tile[32][33];
  const int N = 4096, F = 256;
  float qs = 127.0f / fmaxf(__uint_as_float(*slot), 1e-20f);
  int n0 = blockIdx.x * 32, f0 = blockIdx.y * 32, b = blockIdx.z;
  const float* xb = x + (size_t)b * N * F;
  int8_t* xtb = xt + (size_t)b * N * F;
  int tx = threadIdx.x & 31, ty = threadIdx.x >> 5;  // 32 x 8
#pragma unroll
  for (int i = 0; i < 32; i += 8)
    tile[ty + i][tx] = xb[(size_t)(n0 + ty + i) * F + f0 + tx];
  __syncthreads();
#pragma unroll
  for (int i = 0; i < 32; i += 8) {
    float v = tile[tx][ty + i] * qs;
    xtb[(size_t)(f0 + ty + i) * N + n0 + tx] =
        (int8_t)(int)rintf(fminf(fmaxf(v, -127.f), 127.f));
  }
}

// bf16 -> i8 with scale 127/mx from slot; 8 elems/thread
__global__ void quant8(const bf16_t* __restrict__ in, int8_t* __restrict__ out,
                       const unsigned* __restrict__ slot, size_t n8) {
  size_t i = (size_t)blockIdx.x * blockDim.x + threadIdx.x;
  if (i >= n8) return;
  float qs = 127.0f / fmaxf(__uint_as_float(*slot), 1e-20f);
  bf16x8 v = *(const bf16x8*)(in + i * 8);
  unsigned lo = 0, hi = 0;
#pragma unroll
  for (int j = 0; j < 4; ++j) {
    int q = (int)rintf(fminf(fmaxf((float)v[j] * qs, -127.f), 127.f));
    lo |= (unsigned)(q & 255) << (8 * j);
  }
#pragma unroll
  for (int j = 0; j < 4; ++j) {
    int q = (int)rintf(fminf(fmaxf((float)v[4 + j] * qs, -127.f), 127.f));
    hi |= (unsigned)(q & 255) << (8 * j);
  }
  uint2 r{lo, hi};
  ((uint2*)out)[i] = r;
}

// All three weight transposes in one launch. wt[h*K + k] = bf16(w[k*H + h]).
__global__ void transpose_cast3_kernel(const float* __restrict__ W1, const float* __restrict__ W2,
                                       const float* __restrict__ W3, bf16_t* __restrict__ W1T,
                                       bf16_t* __restrict__ W2T, bf16_t* __restrict__ W3T) {
  const int n1 = 256 * 512;
  const int n2 = 512 * 1024;
  const int n3 = 1024 * 256;
  int idx = blockIdx.x * blockDim.x + threadIdx.x;
  if (idx < n1) {
    int K = 256, H = 512;
    int h = idx / K, k = idx - h * K;
    W1T[idx] = __float2bfloat16(W1[(size_t)k * H + h]);
  } else if (idx < n1 + n2) {
    int i = idx - n1;
    int K = 512, H = 1024;
    int h = i / K, k = i - h * K;
    W2T[i] = __float2bfloat16(W2[(size_t)k * H + h]);
  } else if (idx < n1 + n2 + n3) {
    int i = idx - n1 - n2;
    int K = 1024, H = 256;
    int h = i / K, k = i - h * K;
    W3T[i] = __float2bfloat16(W3[(size_t)k * H + h]);
  }
}

__global__ void init_scales(unsigned* s) {
  if (threadIdx.x < 3) s[threadIdx.x] = 0u;
}

extern "C" void kernel_launch(void* const* d_in, const int* in_sizes, int n_in,
                              void* d_out, int out_size, void* d_ws, size_t ws_size,
                              hipStream_t stream) {
  const float* x   = (const float*)d_in[0];  // [4, 4096, 256]
  const float* adj = (const float*)d_in[1];  // [4096, 4096]
  const float* S   = (const float*)d_in[2];  // [4096, 4096]
  const float* W1  = (const float*)d_in[3];  // [256, 512]
  const float* W2  = (const float*)d_in[4];  // [512, 1024]
  const float* W3  = (const float*)d_in[5];  // [1024, 256]

  const int N = 4096, F = 256, H1 = 512, H2 = 1024, NC = 256, B = 4;

  // Chain (adjacency GEMMs i8, support GEMMs bf16), R7 workspace (~98.5 MiB):
  char* ws = (char*)d_ws;
  int8_t* AWQ  = (int8_t*)ws; ws += (size_t)N * N;           // 16.8 MB
  bf16_t* SCR  = (bf16_t*)ws; ws += (size_t)B * N * H2 * 2;  // 33.5 MB partials/H2B
  int8_t* XQT  = (int8_t*)ws; ws += (size_t)B * F * N;       //  4.2 MB
  bf16_t* BufY = (bf16_t*)ws; ws += (size_t)B * N * H1 * 2;  // 16.8 MB G1/G2/ST3T
  bf16_t* BufZ = (bf16_t*)ws; ws += (size_t)B * N * H1 * 2;  // 16.8 MB H1T/st3 partials
  int8_t* QS   = (int8_t*)ws; ws += (size_t)B * H1 * N;      //  8.4 MB H1Q/ST3Q
  bf16_t* W1T  = (bf16_t*)ws; ws += (size_t)F * H1 * 2;
  bf16_t* W2T  = (bf16_t*)ws; ws += (size_t)H1 * H2 * 2;
  bf16_t* W3T  = (bf16_t*)ws; ws += (size_t)H2 * NC * 2;
  unsigned* SC = (unsigned*)ws;                              // 3 scale slots
  unsigned* SX = SC, *SH1 = SC + 1, *SST3 = SC + 2;

  bf16_t* G1 = BufY, *G2 = BufY, *ST3T = BufY;
  bf16_t* H1T = BufZ;
  bf16_t* H2B = SCR;
  int8_t* H1Q = QS, *ST3Q = QS;

  dim3 blk(THREADS);

  // prep
  init_scales<<<1, 64, 0, stream>>>(SC);
  mul_cast_q<<<(N * N / 4 + 255) / 256, 256, 0, stream>>>(adj, S, AWQ, N * N / 4);
  absmax_f32_h<<<512, 256, 0, stream>>>(x, (size_t)B * N * F / 4, SX);
  transpose_quant_x<<<dim3(N / 32, F / 32, B), 256, 0, stream>>>(x, XQT, SX);
  {
    int total = 256 * 512 + 512 * 1024 + 1024 * 256;
    transpose_cast3_kernel<<<(total + 255) / 256, 256, 0, stream>>>(W1, W2, W3, W1T, W2T, W3T);
  }

  // L1: g1 = AWq @ xq, SK=4 -> partials SCR, reduce -> G1
  gemm_i8<<<dim3(N / BM, F / BN, B * 4), blk, 0, stream>>>(
      AWQ, XQT, SCR, N, F, N, N / 4, 0, (long)F * N, (long)N * F, SX);
  reduce_k<4, false><<<(B * N * F / 8) / 256, 256, 0, stream>>>(
      SCR, G1, (size_t)B * N * F);
  //     h1^T = relu(g1 @ W1)^T -> H1T; then hierarchical absmax + quant
  gemm_bt<1, true><<<dim3(N / BM, H1 / BN, B), blk, 0, stream>>>(
      G1, W1T, H1T, N, H1, F, F, (long)N * F, 0, (long)H1 * N);
  absmax_bf16_h<<<512, 256, 0, stream>>>(H1T, (size_t)B * H1 * N / 8, SH1);
  quant8<<<((int)((size_t)B * H1 * N / 8) + 255) / 256, 256, 0, stream>>>(
      H1T, H1Q, SH1, (size_t)B * H1 * N / 8);

  // L2: g2 = AWq @ h1q, SK=2 -> partials SCR, reduce -> G2
  gemm_i8<<<dim3(N / BM, H1 / BN, B * 2), blk, 0, stream>>>(
      AWQ, H1Q, SCR, N, H1, N, N / 2, 0, (long)H1 * N, (long)N * H1, SH1);
  reduce_k<2, false><<<(B * N * H1 / 8) / 256, 256, 0, stream>>>(
      SCR, G2, (size_t)B * N * H1);
  //     h2 = relu(g2 @ W2) -> H2B (SCR)
  gemm_bt<0, true><<<dim3(N / BM, H2 / BN, B), blk, 0, stream>>>(
      G2, W2T, H2B, N, H2, H1, H1, (long)N * H1, 0, (long)N * H2);

  // L3: st3^T = (h2 @ W3)^T, SK=2 -> partials BufZ, reduce -> ST3T
  gemm_bt<1, false><<<dim3(N / BM, NC / BN, B * 2), blk, 0, stream>>>(
      H2B, W3T, BufZ, N, NC, H2, H2 / 2, (long)N * H2, 0, (long)NC * N);
  reduce_k<2, false><<<(B * NC * N / 8) / 256, 256, 0, stream>>>(
      BufZ, ST3T, (size_t)B * NC * N);
  absmax_bf16_h<<<512, 256, 0, stream>>>(ST3T, (size_t)B * NC * N / 8, SST3);
  quant8<<<((int)((size_t)B * NC * N / 8) + 255) / 256, 256, 0, stream>>>(
      ST3T, ST3Q, SST3, (size_t)B * NC * N / 8);
  //     out = AWq @ st3q, SK=4 -> partials SCR, reduce f32 -> d_out
  gemm_i8<<<dim3(N / BM, NC / BN, B * 4), blk, 0, stream>>>(
      AWQ, ST3Q, SCR, N, NC, N, N / 4, 0, (long)NC * N, (long)N * NC, SST3);
  reduce_k<4, true><<<(B * N * NC / 8) / 256, 256, 0, stream>>>(
      SCR, d_out, (size_t)B * N * NC);
}